// Round 1
// baseline (1323.551 us; speedup 1.0000x reference)
//
#include <hip/hip_runtime.h>
#include <math.h>

// ---------------------------------------------------------------------------
// Branch 1: fused sample (top-40 of 80 cosine sims) + MLP (64->256 relu ->256)
// + L2 normalize. One block per (b, n) pair; 4096 blocks, 256 threads.
// Rows padded 41 -> 44 = 4 mi-groups * 11 rows; thread tile = 11 rows x 4 cols.
// ---------------------------------------------------------------------------
__global__ __launch_bounds__(256) void k_branch1(
    const float* __restrict__ feat1, const int* __restrict__ patch_id1,
    const int* __restrict__ local_id1, const float* __restrict__ W3,
    const float* __restrict__ b3, const float* __restrict__ W4,
    const float* __restrict__ b4, float* __restrict__ out1)
{
    __shared__ __align__(16) float xs[44 * 64];    // gathered rows (padded)
    __shared__ __align__(16) float t1s[44 * 256];  // relu(x @ W3^T + b3)
    __shared__ double sims[80];
    __shared__ int winners[40];
    __shared__ float cen[64];
    __shared__ double cnorm;

    const int row = blockIdx.x;          // 0..4095
    const int b = row >> 9;              // /512
    const int n = row & 511;
    const int tid = threadIdx.x;
    const float* fb = feat1 + (size_t)b * 64 * 16384;   // (C=64, HW=16384)
    const int pid = patch_id1[n];
    const int* lids = local_id1 + n * 80;

    // center row (fr[b, pid, c] = feat1[b, c, pid])
    if (tid < 64) cen[tid] = fb[(size_t)tid * 16384 + pid];
    __syncthreads();

    // center norm (fp64, wave 0)
    if (tid < 64) {
        double v = (double)cen[tid];
        double s = v * v;
        for (int o = 32; o > 0; o >>= 1) s += __shfl_down(s, o);
        if (tid == 0) { s = sqrt(s); cnorm = (s < 1e-12) ? 1e-12 : s; }
    }
    __syncthreads();

    // cosine sims, one local row per thread (fp64 accumulate)
    if (tid < 80) {
        const int lpix = lids[tid];
        double d = 0.0, q = 0.0;
        for (int c = 0; c < 64; ++c) {
            double v = (double)fb[(size_t)c * 16384 + lpix];
            d += v * (double)cen[c];
            q += v * v;
        }
        double nl = sqrt(q); if (nl < 1e-12) nl = 1e-12;
        sims[tid] = d / (nl * cnorm);
    }
    __syncthreads();

    // stable top-40 via rank (matches jax.lax.top_k tie-break: lower idx first)
    if (tid < 80) {
        const double s = sims[tid];
        int rank = 0;
        for (int j = 0; j < 80; ++j) {
            const double sj = sims[j];
            rank += (sj > s) || (sj == s && j < tid);
        }
        if (rank < 40) winners[rank] = tid;
    }
    __syncthreads();

    // gather xs: row 0 = center, rows 1..40 = winners (rank order), 41..43 pad
    for (int m = tid; m < 44 * 64; m += 256) {
        const int mi = m >> 6, c = m & 63;
        float v;
        if (mi >= 1 && mi <= 40) v = fb[(size_t)c * 16384 + lids[winners[mi - 1]]];
        else v = cen[c];
        xs[m] = v;
    }
    __syncthreads();

    const int jg = tid & 63;   // column group (4 consecutive cols)
    const int g = tid >> 6;    // mi-group (one wave each)
    const int j0 = jg * 4;
    const int mb = g * 11;

    // ---- stage 1: t1 = relu(xs @ W3^T + b3), t1s[44][256] ----
    {
        float acc[11][4];
        #pragma unroll
        for (int r = 0; r < 11; ++r) {
            acc[r][0] = 0.f; acc[r][1] = 0.f; acc[r][2] = 0.f; acc[r][3] = 0.f;
        }
        const float4* W3f = (const float4*)W3;   // row j: W3f[j*16 + c4]
        const float4* xsf = (const float4*)xs;   // row mi: xsf[mi*16 + c4]
        #pragma unroll 4
        for (int c4 = 0; c4 < 16; ++c4) {
            const float4 w0 = W3f[(j0 + 0) * 16 + c4];
            const float4 w1 = W3f[(j0 + 1) * 16 + c4];
            const float4 w2 = W3f[(j0 + 2) * 16 + c4];
            const float4 w3 = W3f[(j0 + 3) * 16 + c4];
            #pragma unroll
            for (int r = 0; r < 11; ++r) {
                const float4 x4 = xsf[(mb + r) * 16 + c4];  // LDS broadcast
                acc[r][0] += x4.x*w0.x + x4.y*w0.y + x4.z*w0.z + x4.w*w0.w;
                acc[r][1] += x4.x*w1.x + x4.y*w1.y + x4.z*w1.z + x4.w*w1.w;
                acc[r][2] += x4.x*w2.x + x4.y*w2.y + x4.z*w2.z + x4.w*w2.w;
                acc[r][3] += x4.x*w3.x + x4.y*w3.y + x4.z*w3.z + x4.w*w3.w;
            }
        }
        const float bb0 = b3[j0], bb1 = b3[j0+1], bb2 = b3[j0+2], bb3 = b3[j0+3];
        #pragma unroll
        for (int r = 0; r < 11; ++r) {
            float4 o4;
            o4.x = fmaxf(acc[r][0] + bb0, 0.f);
            o4.y = fmaxf(acc[r][1] + bb1, 0.f);
            o4.z = fmaxf(acc[r][2] + bb2, 0.f);
            o4.w = fmaxf(acc[r][3] + bb3, 0.f);
            *(float4*)&t1s[(mb + r) * 256 + j0] = o4;
        }
    }
    __syncthreads();

    // ---- stage 2: y = t1 @ W4^T + b4, L2-normalize, store ----
    {
        float acc[11][4];
        #pragma unroll
        for (int r = 0; r < 11; ++r) {
            acc[r][0] = 0.f; acc[r][1] = 0.f; acc[r][2] = 0.f; acc[r][3] = 0.f;
        }
        const float4* W4f = (const float4*)W4;   // row j2: W4f[j2*64 + j4]
        const float4* t1f = (const float4*)t1s;  // row mi: t1f[mi*64 + j4]
        #pragma unroll 2
        for (int j4 = 0; j4 < 64; ++j4) {
            const float4 w0 = W4f[(j0 + 0) * 64 + j4];
            const float4 w1 = W4f[(j0 + 1) * 64 + j4];
            const float4 w2 = W4f[(j0 + 2) * 64 + j4];
            const float4 w3 = W4f[(j0 + 3) * 64 + j4];
            #pragma unroll
            for (int r = 0; r < 11; ++r) {
                const float4 t4 = t1f[(mb + r) * 64 + j4];  // LDS broadcast
                acc[r][0] += t4.x*w0.x + t4.y*w0.y + t4.z*w0.z + t4.w*w0.w;
                acc[r][1] += t4.x*w1.x + t4.y*w1.y + t4.z*w1.z + t4.w*w1.w;
                acc[r][2] += t4.x*w2.x + t4.y*w2.y + t4.z*w2.z + t4.w*w2.w;
                acc[r][3] += t4.x*w3.x + t4.y*w3.y + t4.z*w3.z + t4.w*w3.w;
            }
        }
        const float bb0 = b4[j0], bb1 = b4[j0+1], bb2 = b4[j0+2], bb3 = b4[j0+3];
        #pragma unroll
        for (int r = 0; r < 11; ++r) {
            const float y0 = acc[r][0] + bb0;
            const float y1 = acc[r][1] + bb1;
            const float y2 = acc[r][2] + bb2;
            const float y3 = acc[r][3] + bb3;
            float p = y0*y0 + y1*y1 + y2*y2 + y3*y3;
            // row norm across the wave (64 lanes x 4 cols = 256)
            for (int o = 1; o < 64; o <<= 1) p += __shfl_xor(p, o);
            const float inv = 1.f / (sqrtf(p) + 1e-7f);
            const int mi = mb + r;
            if (mi < 41) {
                float4 o4 = make_float4(y0*inv, y1*inv, y2*inv, y3*inv);
                *(float4*)&out1[((size_t)row * 41 + mi) * 256 + j0] = o4;
            }
        }
    }
}

// ---------------------------------------------------------------------------
// Branch 0 kernels
// ---------------------------------------------------------------------------
__global__ __launch_bounds__(64) void k_sample0(
    const float* __restrict__ feat0, const int* __restrict__ patch_id0,
    const int* __restrict__ local_id0, float* __restrict__ x0m)
{
    __shared__ float cen[512];
    __shared__ float loc[8][512];
    __shared__ double sims[8];
    __shared__ int winners[4];
    __shared__ double cnorm;

    const int row = blockIdx.x;          // 0..511
    const int b = row >> 6;
    const int n = row & 63;
    const int t = threadIdx.x;           // 64
    const float* fb = feat0 + (size_t)b * 512 * 64;   // (C=512, HW=64)
    const int pid = patch_id0[n];

    for (int c = t; c < 512; c += 64) cen[c] = fb[(size_t)c * 64 + pid];
    for (int l = 0; l < 8; ++l) {
        const int lp = local_id0[n * 8 + l];
        for (int c = t; c < 512; c += 64) loc[l][c] = fb[(size_t)c * 64 + lp];
    }
    __syncthreads();

    double cs = 0.0;
    for (int c = t; c < 512; c += 64) { double v = (double)cen[c]; cs += v * v; }
    for (int o = 32; o > 0; o >>= 1) cs += __shfl_down(cs, o);
    if (t == 0) { cs = sqrt(cs); cnorm = (cs < 1e-12) ? 1e-12 : cs; }
    __syncthreads();

    for (int l = 0; l < 8; ++l) {
        double d = 0.0, q = 0.0;
        for (int c = t; c < 512; c += 64) {
            double v = (double)loc[l][c];
            d += v * (double)cen[c];
            q += v * v;
        }
        for (int o = 32; o > 0; o >>= 1) { d += __shfl_down(d, o); q += __shfl_down(q, o); }
        if (t == 0) {
            double nl = sqrt(q); if (nl < 1e-12) nl = 1e-12;
            sims[l] = d / (nl * cnorm);
        }
    }
    __syncthreads();

    if (t < 8) {
        const double s = sims[t];
        int rank = 0;
        for (int j = 0; j < 8; ++j) {
            const double sj = sims[j];
            rank += (sj > s) || (sj == s && j < t);
        }
        if (rank < 4) winners[rank] = t;
    }
    __syncthreads();

    for (int c = t; c < 512; c += 64) {
        float a = cen[c];
        for (int r = 0; r < 4; ++r) a += loc[winners[r]][c];
        x0m[(size_t)row * 512 + c] = a * 0.2f;   // mean over 5 rows
    }
}

__global__ __launch_bounds__(256) void k_gemm1(
    const float* __restrict__ x, const float* __restrict__ W1,
    const float* __restrict__ b1, float* __restrict__ h)
{
    __shared__ __align__(16) float xsr[512];
    const int i = blockIdx.y;
    const int j = blockIdx.x * 256 + threadIdx.x;   // 0..1023
    for (int c = threadIdx.x; c < 512; c += 256) xsr[c] = x[(size_t)i * 512 + c];
    __syncthreads();
    const float4* wr = (const float4*)(W1 + (size_t)j * 512);
    const float4* xr = (const float4*)xsr;
    float acc = 0.f;
    #pragma unroll 4
    for (int k = 0; k < 128; ++k) {
        const float4 w = wr[k]; const float4 a = xr[k];
        acc += a.x*w.x + a.y*w.y + a.z*w.z + a.w*w.w;
    }
    h[(size_t)i * 1024 + j] = acc + b1[j];
}

__global__ __launch_bounds__(64) void k_bnstats(
    const float* __restrict__ h, float* __restrict__ mu, float* __restrict__ rstd)
{
    const int j = blockIdx.x;   // 0..1023
    const int t = threadIdx.x;  // 64
    float s = 0.f, ss = 0.f;
    for (int i = t; i < 512; i += 64) {
        const float v = h[(size_t)i * 1024 + j];
        s += v; ss += v * v;
    }
    for (int o = 32; o > 0; o >>= 1) { s += __shfl_down(s, o); ss += __shfl_down(ss, o); }
    if (t == 0) {
        const float m = s * (1.f / 512.f);
        const float var = ss * (1.f / 512.f) - m * m;   // biased, matches jnp.var
        mu[j] = m;
        rstd[j] = rsqrtf(var + 1e-5f);
    }
}

__global__ __launch_bounds__(256) void k_bnapply(
    float* __restrict__ h, const float* __restrict__ mu, const float* __restrict__ rstd,
    const float* __restrict__ gamma, const float* __restrict__ beta)
{
    const int e = blockIdx.x * 256 + threadIdx.x;   // 0..131071 float4s
    const int jb = (e & 255) * 4;
    float4 v = ((float4*)h)[e];
    v.x = fmaxf((v.x - mu[jb+0]) * rstd[jb+0] * gamma[jb+0] + beta[jb+0], 0.f);
    v.y = fmaxf((v.y - mu[jb+1]) * rstd[jb+1] * gamma[jb+1] + beta[jb+1], 0.f);
    v.z = fmaxf((v.z - mu[jb+2]) * rstd[jb+2] * gamma[jb+2] + beta[jb+2], 0.f);
    v.w = fmaxf((v.w - mu[jb+3]) * rstd[jb+3] * gamma[jb+3] + beta[jb+3], 0.f);
    ((float4*)h)[e] = v;
}

__global__ __launch_bounds__(256) void k_gemm2(
    const float* __restrict__ h, const float* __restrict__ W2,
    const float* __restrict__ b2, float* __restrict__ out0)
{
    __shared__ __align__(16) float hs[1024];
    const int i = blockIdx.x;       // 0..511
    const int j = threadIdx.x;      // 0..255
    for (int c = threadIdx.x; c < 1024; c += 256) hs[c] = h[(size_t)i * 1024 + c];
    __syncthreads();
    const float4* wr = (const float4*)(W2 + (size_t)j * 1024);
    const float4* hr = (const float4*)hs;
    float acc = 0.f;
    #pragma unroll 4
    for (int k = 0; k < 256; ++k) {
        const float4 w = wr[k]; const float4 a = hr[k];
        acc += a.x*w.x + a.y*w.y + a.z*w.z + a.w*w.w;
    }
    out0[(size_t)i * 256 + j] = acc + b2[j];
}

// ---------------------------------------------------------------------------
extern "C" void kernel_launch(void* const* d_in, const int* in_sizes, int n_in,
                              void* d_out, int out_size, void* d_ws, size_t ws_size,
                              hipStream_t stream) {
    const float* feat0 = (const float*)d_in[0];
    const float* feat1 = (const float*)d_in[1];
    const float* W1    = (const float*)d_in[2];
    const float* b1    = (const float*)d_in[3];
    const float* gamma = (const float*)d_in[4];
    const float* beta  = (const float*)d_in[5];
    const float* W2    = (const float*)d_in[6];
    const float* b2    = (const float*)d_in[7];
    const float* W3    = (const float*)d_in[8];
    const float* b3    = (const float*)d_in[9];
    const float* W4    = (const float*)d_in[10];
    const float* b4    = (const float*)d_in[11];
    const int* patch_id0 = (const int*)d_in[12];
    const int* patch_id1 = (const int*)d_in[13];
    const int* local_id0 = (const int*)d_in[14];
    const int* local_id1 = (const int*)d_in[15];

    float* out0 = (float*)d_out;                 // (512, 256)
    float* out1 = out0 + 512 * 256;              // (4096, 41, 256)

    float* ws   = (float*)d_ws;
    float* x0m  = ws;               // 512*512
    float* h    = ws + 262144;      // 512*1024
    float* mu   = ws + 786432;      // 1024
    float* rstd = ws + 787456;      // 1024

    // dominant kernel first
    k_branch1<<<4096, 256, 0, stream>>>(feat1, patch_id1, local_id1, W3, b3, W4, b4, out1);

    // branch 0 chain
    k_sample0<<<512, 64, 0, stream>>>(feat0, patch_id0, local_id0, x0m);
    k_gemm1<<<dim3(4, 512), 256, 0, stream>>>(x0m, W1, b1, h);
    k_bnstats<<<1024, 64, 0, stream>>>(h, mu, rstd);
    k_bnapply<<<512, 256, 0, stream>>>(h, mu, rstd, gamma, beta);
    k_gemm2<<<512, 256, 0, stream>>>(h, W2, b2, out0);
}